// Round 11
// baseline (14488.652 us; speedup 1.0000x reference)
//
#include <hip/hip_runtime.h>

#define N_TOTAL 150000   // N_USERS + M_ITEMS
#define DIM 64
#define RPB 293          // rows per bucket
#define NBUCK 512        // buckets == co-resident block slots (2/CU x 256)
#define MAGIC 14658592u  // ceil(2^32/293): __umulhi(r,MAGIC) == r/293 exact for r<2^24
#define CAP 10368        // bucket capacity (mean 9375 + ~10 sigma)
#define CHUNK 8192       // edges per binning block (512 thr x 16)
#define ASTRIDE 65       // acc row stride (floats): bank-spread, 65%32==1

typedef float v2f __attribute__((ext_vector_type(2)));

__global__ void fill_bcur_kernel(int* __restrict__ bcur) {
    int t = blockIdx.x * 256 + threadIdx.x;
    if (t < NBUCK) bcur[t] = t * CAP;
}

// Phase B: LDS-sorted multisplit into 512 row-range buckets; coalesced stream-out.
// record: pk.x = rowLocal(9b)<<18 | col(18b) ; pk.y = f32 val bits
__global__ void bin_kernel(const int* __restrict__ idx, const float* __restrict__ val,
                           int* __restrict__ bcur, uint2* __restrict__ binned, int nnz) {
    __shared__ uint2 sedge[CHUNK];        // 64 KB
    __shared__ int lcnt[NBUCK];
    __shared__ int lstart[NBUCK + 1];
    __shared__ int gbase[NBUCK];
    int t = threadIdx.x;
    int base = blockIdx.x * CHUNK;
    int nEdges = min(CHUNK, nnz - base);
    lcnt[t] = 0;
    __syncthreads();
    uint2 myedge[16];
    int myb[16];
    #pragma unroll
    for (int i = 0; i < 16; ++i) {
        int e = base + t + i * 512;
        if (e < nnz) {
            int r = idx[e];
            int b = (int)__umulhi((unsigned)r, MAGIC);
            myb[i] = b;
            unsigned rl = (unsigned)(r - b * RPB);
            myedge[i].x = (rl << 18) | (unsigned)idx[nnz + e];
            myedge[i].y = __float_as_uint(val[e]);
            atomicAdd(&lcnt[b], 1);
        } else {
            myb[i] = -1;
        }
    }
    __syncthreads();
    int c = lcnt[t];
    lstart[t] = c;
    __syncthreads();
    for (int off = 1; off < 512; off <<= 1) {
        int x = (t >= off) ? lstart[t - off] : 0;
        __syncthreads();
        lstart[t] += x;
        __syncthreads();
    }
    int incl = lstart[t];
    __syncthreads();
    lstart[t] = incl - c;                  // exclusive
    if (t == 511) lstart[512] = incl;      // total
    gbase[t] = c ? atomicAdd(&bcur[t], c) : 0;
    lcnt[t] = 0;                           // reuse as placement cursor
    __syncthreads();
    #pragma unroll
    for (int i = 0; i < 16; ++i) {
        int b = myb[i];
        if (b >= 0) {
            int o = atomicAdd(&lcnt[b], 1);
            sedge[lstart[b] + o] = myedge[i];
        }
    }
    __syncthreads();
    for (int p = t; p < nEdges; p += 512) {
        int lo = 0, hi = NBUCK;
        while (hi - lo > 1) {
            int mid = (lo + hi) >> 1;
            if (lstart[mid] <= p) lo = mid; else hi = mid;
        }
        int dst = gbase[lo] + (p - lstart[lo]);
        if (dst < (lo + 1) * CAP)          // overflow guard (never hit)
            binned[dst] = sedge[p];
    }
}

// Phase C: per-bucket COLUMN sort (512 col-bins) -> cs (col<<14|val14) + rl (ushort).
// Col-sorted order makes the 512 co-resident spmm blocks sweep the gather table
// in a synchronized band (L2-resident).
__global__ void scatterc_kernel(const uint2* __restrict__ binned, const int* __restrict__ bcur,
                                unsigned short* __restrict__ rl, unsigned* __restrict__ cs) {
    __shared__ int hist[NBUCK];
    __shared__ int ssc[256];
    int b = blockIdx.x, t = threadIdx.x;
    int s = b * CAP, e = min(bcur[b], s + CAP);
    hist[t] = 0; hist[t + 256] = 0;
    __syncthreads();
    for (int k = s + t; k < e; k += 256) {
        unsigned col = binned[k].x & 0x3FFFFu;
        atomicAdd(&hist[__umulhi(col, MAGIC)], 1);
    }
    __syncthreads();
    int i0 = 2 * t;
    int c0 = hist[i0], c1 = hist[i0 + 1];
    int s2 = c0 + c1;
    ssc[t] = s2;
    __syncthreads();
    for (int off = 1; off < 256; off <<= 1) {
        int x = (t >= off) ? ssc[t - off] : 0;
        __syncthreads();
        ssc[t] += x;
        __syncthreads();
    }
    int excl = ssc[t] - s2;
    __syncthreads();
    hist[i0] = excl;
    hist[i0 + 1] = excl + c0;
    __syncthreads();
    for (int k = s + t; k < e; k += 256) {
        uint2 ed = binned[k];
        unsigned col = ed.x & 0x3FFFFu;
        int cb = (int)__umulhi(col, MAGIC);
        int o = atomicAdd(&hist[cb], 1);
        unsigned v14 = (ed.y + 0x20000u) >> 18;   // round f32 -> 14-bit float
        cs[s + o] = (col << 14) | v14;
        rl[s + o] = (unsigned short)(ed.x >> 18);
    }
}

// ---- out = sum_f (w[f]/4) * emb_f (exact f32 layer-0 contribution) ----
__global__ void init_out_kernel(const float* __restrict__ e0, const float* __restrict__ e1,
                                const float* __restrict__ e2, const float* __restrict__ w,
                                float* __restrict__ out, int n4) {
    int i = blockIdx.x * blockDim.x + threadIdx.x;
    if (i >= n4) return;
    float c0 = w[0] * 0.25f, c1 = w[1] * 0.25f, c2 = w[2] * 0.25f;
    float4 a = reinterpret_cast<const float4*>(e0)[i];
    float4 b = reinterpret_cast<const float4*>(e1)[i];
    float4 c = reinterpret_cast<const float4*>(e2)[i];
    float4 o;
    o.x = c0 * a.x + c1 * b.x + c2 * c.x;
    o.y = c0 * a.y + c1 * b.y + c2 * c.y;
    o.z = c0 * a.z + c1 * b.z + c2 * c.z;
    o.w = c0 * a.w + c1 * b.w + c2 * c.w;
    reinterpret_cast<float4*>(out)[i] = o;
}

// f32 -> fp8(e4m3, x64 scale) DIM-PERMUTED table: word w of a row packs dims
// {w, w+16, w+32, w+48}. Makes the 4 LDS adds per lane bank-conflict-free.
__global__ void conv_fp8_kernel(const float* __restrict__ x, unsigned* __restrict__ y,
                                int nwords) {
    int i = blockIdx.x * blockDim.x + threadIdx.x;
    if (i >= nwords) return;
    int row = i >> 4, w = i & 15;
    const float* xr = x + ((size_t)row << 6) + w;
    int p = __builtin_amdgcn_cvt_pk_fp8_f32(xr[0] * 64.f, xr[16] * 64.f, 0, false);
    p = __builtin_amdgcn_cvt_pk_fp8_f32(xr[32] * 64.f, xr[48] * 64.f, p, true);
    y[i] = (unsigned)p;
}

// ---- bucket-resident sweep SpMM. One block per bucket (512 blocks == slots).
// LDS acc[293][65] f32; col-sorted edges; quarter-wave (16 lanes) per edge;
// ds_add_f32 accumulate. Epilogue: y fp8 pack + fused out RMW. ----
template <bool LAST>
__global__ __launch_bounds__(256)
void spmm_fp8_kernel(const unsigned short* __restrict__ rl, const unsigned* __restrict__ cs,
                     const int* __restrict__ bcur, const unsigned* __restrict__ x,
                     unsigned* __restrict__ y, float* __restrict__ out,
                     const float* __restrict__ w, int f) {
    __shared__ float acc[RPB * ASTRIDE];   // 76,180 B -> 2 blocks/CU
    int b = blockIdx.x;
    int t = threadIdx.x;
    int s = b * CAP;
    int e = min(bcur[b], s + CAP);
    for (int i = t; i < RPB * ASTRIDE; i += 256) acc[i] = 0.f;
    __syncthreads();
    int wid = t >> 6, q = (t >> 4) & 3, sub = t & 15;
    #pragma unroll 2
    for (int kb = s + wid * 4 + q; kb < e; kb += 16) {
        unsigned ed = cs[kb];
        int r = rl[kb];
        unsigned g = x[((size_t)(ed >> 14) << 4) + sub];
        float vv = __uint_as_float((ed & 0x3FFFu) << 18);
        v2f lo = __builtin_amdgcn_cvt_pk_f32_fp8((int)g, false);
        v2f hi = __builtin_amdgcn_cvt_pk_f32_fp8((int)g, true);
        float* a = &acc[r * ASTRIDE + sub];
        atomicAdd(a, vv * lo.x);
        atomicAdd(a + 16, vv * lo.y);
        atomicAdd(a + 32, vv * hi.x);
        atomicAdd(a + 48, vv * hi.y);
    }
    __syncthreads();
    float c = w[f] * (0.25f / 64.f);
    int wd = t & 15;
    for (int rr = (t >> 4); rr < RPB; rr += 16) {
        int row = b * RPB + rr;
        if (row >= N_TOTAL) break;
        float a0 = acc[rr * ASTRIDE + wd];
        float a1 = acc[rr * ASTRIDE + wd + 16];
        float a2 = acc[rr * ASTRIDE + wd + 32];
        float a3 = acc[rr * ASTRIDE + wd + 48];
        if (!LAST) {
            int p = __builtin_amdgcn_cvt_pk_fp8_f32(a0, a1, 0, false);
            p = __builtin_amdgcn_cvt_pk_fp8_f32(a2, a3, p, true);
            y[((size_t)row << 4) + wd] = (unsigned)p;
        }
        float* o = out + ((size_t)row << 6) + wd;
        o[0]  += c * a0;
        o[16] += c * a1;
        o[32] += c * a2;
        o[48] += c * a3;
    }
}

extern "C" void kernel_launch(void* const* d_in, const int* in_sizes, int n_in,
                              void* d_out, int out_size, void* d_ws, size_t ws_size,
                              hipStream_t stream) {
    const float* emb[3]  = {(const float*)d_in[0], (const float*)d_in[1], (const float*)d_in[2]};
    const int*   gidx[3] = {(const int*)d_in[3],   (const int*)d_in[5],   (const int*)d_in[7]};
    const float* gval[3] = {(const float*)d_in[4], (const float*)d_in[6], (const float*)d_in[8]};
    const float* w = (const float*)d_in[9];
    float* out = (float*)d_out;

    const int nnz = in_sizes[4];
    const size_t bufElems = (size_t)N_TOTAL * DIM;       // 9.6M
    const size_t fp8Bytes = bufElems;                    // 9.6 MB per table
    const size_t capElems = (size_t)NBUCK * CAP;         // 5.31M entries

    // ws layout:
    //   [0, 42.5MB)       binned (uint2) -- aliases {emb8, bufA8, bufB8} (28.8MB)
    //   [42.5, 63.7MB)    cs (u32, bucket-strided, col-sorted)
    //   [63.7, 74.3MB)    rl (u16)
    //   then bcur
    char* base = (char*)d_ws;
    uint2*          binned = (uint2*)base;
    unsigned*       emb8   = (unsigned*)base;                  // live after scatterc
    unsigned*       bufA8  = (unsigned*)(base + fp8Bytes);     // live after spmm L1
    unsigned*       bufB8  = (unsigned*)(base + 2 * fp8Bytes); // live after spmm L2
    unsigned*       cs     = (unsigned*)(base + capElems * 8);
    unsigned short* rl     = (unsigned short*)(base + capElems * 8 + capElems * 4);
    int*            bcur   = (int*)(base + capElems * 8 + capElems * 4 + capElems * 2);

    const int n4 = (int)(bufElems / 4);
    const int nwords = (int)(bufElems / 4);               // N_TOTAL*16
    dim3 eltGrid((n4 + 255) / 256);
    dim3 cvtGrid((nwords + 255) / 256);
    dim3 chunkGrid((nnz + CHUNK - 1) / CHUNK);            // 586

    // layer-0 contributions of all factors in one pass (exact f32)
    init_out_kernel<<<eltGrid, 256, 0, stream>>>(emb[0], emb[1], emb[2], w, out, n4);

    for (int f = 0; f < 3; ++f) {
        // --- bucket build ---
        fill_bcur_kernel<<<2, 256, 0, stream>>>(bcur);
        bin_kernel<<<chunkGrid, 512, 0, stream>>>(gidx[f], gval[f], bcur, binned, nnz);
        scatterc_kernel<<<NBUCK, 256, 0, stream>>>(binned, bcur, rl, cs);

        // --- fp8 dim-permuted table of this factor's embedding ---
        conv_fp8_kernel<<<cvtGrid, 256, 0, stream>>>(emb[f], emb8, nwords);

        // --- 3 propagation layers, axpy fused into epilogue ---
        spmm_fp8_kernel<false><<<NBUCK, 256, 0, stream>>>(rl, cs, bcur, emb8, bufA8,
                                                          out, w, f);
        spmm_fp8_kernel<false><<<NBUCK, 256, 0, stream>>>(rl, cs, bcur, bufA8, bufB8,
                                                          out, w, f);
        spmm_fp8_kernel<true><<<NBUCK, 256, 0, stream>>>(rl, cs, bcur, bufB8, nullptr,
                                                         out, w, f);
    }
}

// Round 12
// 2688.034 us; speedup vs baseline: 5.3901x; 5.3901x over previous
//
#include <hip/hip_runtime.h>

#define N_TOTAL 150000   // N_USERS + M_ITEMS
#define DIM 64
#define RPB 293          // rows per bucket
#define NBUCK 512        // buckets == co-resident block slots
#define MAGIC 14658592u  // ceil(2^32/293): __umulhi(r,MAGIC) == r/293 for r<2^24
#define CAP 10368        // bucket capacity (mean 9375 + ~10 sigma)
#define CHUNK 8192       // edges per binning block (512 thr x 16)
#define ASTRIDE 65       // acc row stride (floats): 65%32==1 -> bank spread

typedef float v2f __attribute__((ext_vector_type(2)));

__global__ void fill_bcur_kernel(int* __restrict__ bcur) {
    int t = blockIdx.x * 256 + threadIdx.x;
    if (t < NBUCK) bcur[t] = t * CAP;
}

// Phase B: LDS-sorted multisplit into 512 row-range buckets; coalesced stream-out.
// record: pk.x = rowLocal(9b)<<18 | col(18b) ; pk.y = f32 val bits
__global__ void bin_kernel(const int* __restrict__ idx, const float* __restrict__ val,
                           int* __restrict__ bcur, uint2* __restrict__ binned, int nnz) {
    __shared__ uint2 sedge[CHUNK];        // 64 KB
    __shared__ int lcnt[NBUCK];
    __shared__ int lstart[NBUCK + 1];
    __shared__ int gbase[NBUCK];
    int t = threadIdx.x;
    int base = blockIdx.x * CHUNK;
    int nEdges = min(CHUNK, nnz - base);
    lcnt[t] = 0;
    __syncthreads();
    uint2 myedge[16];
    int myb[16];
    #pragma unroll
    for (int i = 0; i < 16; ++i) {
        int e = base + t + i * 512;
        if (e < nnz) {
            int r = idx[e];
            int b = (int)__umulhi((unsigned)r, MAGIC);
            myb[i] = b;
            unsigned rloc = (unsigned)(r - b * RPB);
            myedge[i].x = (rloc << 18) | (unsigned)idx[nnz + e];
            myedge[i].y = __float_as_uint(val[e]);
            atomicAdd(&lcnt[b], 1);
        } else {
            myb[i] = -1;
        }
    }
    __syncthreads();
    int c = lcnt[t];
    lstart[t] = c;
    __syncthreads();
    for (int off = 1; off < 512; off <<= 1) {
        int x = (t >= off) ? lstart[t - off] : 0;
        __syncthreads();
        lstart[t] += x;
        __syncthreads();
    }
    int incl = lstart[t];
    __syncthreads();
    lstart[t] = incl - c;                  // exclusive
    if (t == 511) lstart[512] = incl;      // total
    gbase[t] = c ? atomicAdd(&bcur[t], c) : 0;
    lcnt[t] = 0;                           // reuse as placement cursor
    __syncthreads();
    #pragma unroll
    for (int i = 0; i < 16; ++i) {
        int b = myb[i];
        if (b >= 0) {
            int o = atomicAdd(&lcnt[b], 1);
            sedge[lstart[b] + o] = myedge[i];
        }
    }
    __syncthreads();
    for (int p = t; p < nEdges; p += 512) {
        int lo = 0, hi = NBUCK;
        while (hi - lo > 1) {
            int mid = (lo + hi) >> 1;
            if (lstart[mid] <= p) lo = mid; else hi = mid;
        }
        int dst = gbase[lo] + (p - lstart[lo]);
        if (dst < (lo + 1) * CAP)          // overflow guard (never hit)
            binned[dst] = sedge[p];
    }
}

// Phase C (col variant): per-bucket COLUMN sort -> cs (col<<14|val14) + rl (u16).
__global__ void scatterc_col_kernel(const uint2* __restrict__ binned,
                                    const int* __restrict__ bcur,
                                    unsigned short* __restrict__ rl,
                                    unsigned* __restrict__ cs) {
    __shared__ int hist[NBUCK];
    __shared__ int ssc[256];
    int b = blockIdx.x, t = threadIdx.x;
    int s = b * CAP, e = min(bcur[b], s + CAP);
    hist[t] = 0; hist[t + 256] = 0;
    __syncthreads();
    for (int k = s + t; k < e; k += 256) {
        unsigned col = binned[k].x & 0x3FFFFu;
        atomicAdd(&hist[__umulhi(col, MAGIC)], 1);
    }
    __syncthreads();
    int i0 = 2 * t;
    int c0 = hist[i0], c1 = hist[i0 + 1];
    int s2 = c0 + c1;
    ssc[t] = s2;
    __syncthreads();
    for (int off = 1; off < 256; off <<= 1) {
        int x = (t >= off) ? ssc[t - off] : 0;
        __syncthreads();
        ssc[t] += x;
        __syncthreads();
    }
    int excl = ssc[t] - s2;
    __syncthreads();
    hist[i0] = s + excl;
    hist[i0 + 1] = s + excl + c0;
    __syncthreads();
    for (int k = s + t; k < e; k += 256) {
        uint2 ed = binned[k];
        unsigned col = ed.x & 0x3FFFFu;
        int cb = (int)__umulhi(col, MAGIC);
        int o = atomicAdd(&hist[cb], 1);
        unsigned v14 = (ed.y + 0x20000u) >> 18;   // round f32 -> 14-bit float
        cs[o] = (col << 14) | v14;
        rl[o] = (unsigned short)(ed.x >> 18);
    }
}

// Phase C (row variant): per-bucket ROW-grouped CSR -> cs + rlo/rhi (absolute).
__global__ void scatterc_row_kernel(const uint2* __restrict__ binned,
                                    const int* __restrict__ bcur,
                                    int* __restrict__ rlo, int* __restrict__ rhi,
                                    unsigned* __restrict__ cs) {
    __shared__ int hist[RPB];
    __shared__ int ssc[256];
    int b = blockIdx.x, t = threadIdx.x;
    int s = b * CAP, e = min(bcur[b], s + CAP);
    for (int i = t; i < RPB; i += 256) hist[i] = 0;
    __syncthreads();
    for (int k = s + t; k < e; k += 256)
        atomicAdd(&hist[binned[k].x >> 18], 1);
    __syncthreads();
    int i0 = 2 * t;
    int c0 = (i0 < RPB) ? hist[i0] : 0;
    int c1 = (i0 + 1 < RPB) ? hist[i0 + 1] : 0;
    int s2 = c0 + c1;
    ssc[t] = s2;
    __syncthreads();
    for (int off = 1; off < 256; off <<= 1) {
        int x = (t >= off) ? ssc[t - off] : 0;
        __syncthreads();
        ssc[t] += x;
        __syncthreads();
    }
    int excl = ssc[t] - s2;
    __syncthreads();
    int base0 = s + excl, base1 = s + excl + c0;
    if (i0 < RPB) {
        int row = b * RPB + i0;
        if (row < N_TOTAL) { rlo[row] = base0; rhi[row] = base0 + c0; }
        hist[i0] = base0;
    }
    if (i0 + 1 < RPB) {
        int row = b * RPB + i0 + 1;
        if (row < N_TOTAL) { rlo[row] = base1; rhi[row] = base1 + c1; }
        hist[i0 + 1] = base1;
    }
    __syncthreads();
    for (int k = s + t; k < e; k += 256) {
        uint2 ed = binned[k];
        int rl_ = ed.x >> 18;
        int o = atomicAdd(&hist[rl_], 1);
        unsigned v14 = (ed.y + 0x20000u) >> 18;
        cs[o] = ((ed.x & 0x3FFFFu) << 14) | v14;
    }
}

// ---- out = sum_f (w[f]/4) * emb_f (exact f32 layer-0 contribution) ----
__global__ void init_out_kernel(const float* __restrict__ e0, const float* __restrict__ e1,
                                const float* __restrict__ e2, const float* __restrict__ w,
                                float* __restrict__ out, int n4) {
    int i = blockIdx.x * blockDim.x + threadIdx.x;
    if (i >= n4) return;
    float c0 = w[0] * 0.25f, c1 = w[1] * 0.25f, c2 = w[2] * 0.25f;
    float4 a = reinterpret_cast<const float4*>(e0)[i];
    float4 b = reinterpret_cast<const float4*>(e1)[i];
    float4 c = reinterpret_cast<const float4*>(e2)[i];
    float4 o;
    o.x = c0 * a.x + c1 * b.x + c2 * c.x;
    o.y = c0 * a.y + c1 * b.y + c2 * c.y;
    o.z = c0 * a.z + c1 * b.z + c2 * c.z;
    o.w = c0 * a.w + c1 * b.w + c2 * c.w;
    reinterpret_cast<float4*>(out)[i] = o;
}

// f32 -> fp8(e4m3, x64 scale) LINEAR table (word wd = dims 4wd..4wd+3).
__global__ void conv_fp8_kernel(const float* __restrict__ x, uint2* __restrict__ y, int n8) {
    int i = blockIdx.x * blockDim.x + threadIdx.x;
    if (i >= n8) return;
    const float4* x4 = reinterpret_cast<const float4*>(x);
    float4 a = x4[2 * i], b = x4[2 * i + 1];
    int p0 = __builtin_amdgcn_cvt_pk_fp8_f32(a.x * 64.f, a.y * 64.f, 0, false);
    p0 = __builtin_amdgcn_cvt_pk_fp8_f32(a.z * 64.f, a.w * 64.f, p0, true);
    int p1 = __builtin_amdgcn_cvt_pk_fp8_f32(b.x * 64.f, b.y * 64.f, 0, false);
    p1 = __builtin_amdgcn_cvt_pk_fp8_f32(b.z * 64.f, b.w * 64.f, p1, true);
    uint2 o;
    o.x = (unsigned)p0;
    o.y = (unsigned)p1;
    y[i] = o;
}

// ---- register-accumulator pull SpMM (round-9 proven, 90us) ----
template <bool LAST>
__global__ void spmm_reg_kernel(const int* __restrict__ rlo, const int* __restrict__ rhi,
                                const unsigned* __restrict__ cs, const unsigned* __restrict__ x,
                                unsigned* __restrict__ y, float* __restrict__ out,
                                const float* __restrict__ w, int f, int nrows) {
    int gid = blockIdx.x * blockDim.x + threadIdx.x;
    int row = gid >> 6;
    int lane = gid & 63;
    if (row >= nrows) return;
    int s = rlo[row], e = rhi[row];
    int q = lane >> 4, sub = lane & 15;
    float ac[4][4];
    #pragma unroll
    for (int j = 0; j < 4; ++j) {
        ac[j][0] = 0.f; ac[j][1] = 0.f; ac[j][2] = 0.f; ac[j][3] = 0.f;
    }
    int k = s + q;
    for (; k + 12 < e; k += 16) {
        unsigned ed[4], g[4];
        #pragma unroll
        for (int j = 0; j < 4; ++j) ed[j] = cs[k + 4 * j];
        #pragma unroll
        for (int j = 0; j < 4; ++j) g[j] = x[((size_t)(ed[j] >> 14) << 4) + sub];
        #pragma unroll
        for (int j = 0; j < 4; ++j) {
            float vv = __uint_as_float((ed[j] & 0x3FFFu) << 18);
            v2f lo = __builtin_amdgcn_cvt_pk_f32_fp8((int)g[j], false);
            v2f hi = __builtin_amdgcn_cvt_pk_f32_fp8((int)g[j], true);
            ac[j][0] += vv * lo.x;
            ac[j][1] += vv * lo.y;
            ac[j][2] += vv * hi.x;
            ac[j][3] += vv * hi.y;
        }
    }
    for (; k < e; k += 4) {
        unsigned ed = cs[k];
        unsigned g = x[((size_t)(ed >> 14) << 4) + sub];
        float vv = __uint_as_float((ed & 0x3FFFu) << 18);
        v2f lo = __builtin_amdgcn_cvt_pk_f32_fp8((int)g, false);
        v2f hi = __builtin_amdgcn_cvt_pk_f32_fp8((int)g, true);
        ac[0][0] += vv * lo.x;
        ac[0][1] += vv * lo.y;
        ac[0][2] += vv * hi.x;
        ac[0][3] += vv * hi.y;
    }
    float a0 = (ac[0][0] + ac[1][0]) + (ac[2][0] + ac[3][0]);
    float a1 = (ac[0][1] + ac[1][1]) + (ac[2][1] + ac[3][1]);
    float a2 = (ac[0][2] + ac[1][2]) + (ac[2][2] + ac[3][2]);
    float a3 = (ac[0][3] + ac[1][3]) + (ac[2][3] + ac[3][3]);
    a0 += __shfl_xor(a0, 16); a0 += __shfl_xor(a0, 32);
    a1 += __shfl_xor(a1, 16); a1 += __shfl_xor(a1, 32);
    a2 += __shfl_xor(a2, 16); a2 += __shfl_xor(a2, 32);
    a3 += __shfl_xor(a3, 16); a3 += __shfl_xor(a3, 32);
    if (q == 0) {
        if (!LAST) {
            int p = __builtin_amdgcn_cvt_pk_fp8_f32(a0, a1, 0, false);
            p = __builtin_amdgcn_cvt_pk_fp8_f32(a2, a3, p, true);
            y[((size_t)row << 4) + sub] = (unsigned)p;
        }
        float c = w[f] * (0.25f / 64.f);
        float4* o4 = reinterpret_cast<float4*>(out) + (((size_t)row << 4) + sub);
        float4 cv = *o4;
        cv.x += c * a0;
        cv.y += c * a1;
        cv.z += c * a2;
        cv.w += c * a3;
        *o4 = cv;
    }
}

// ---- bucket-resident SWEEP SpMM (col-sorted edges; LDS f32 accumulators via
// __hip_atomic_fetch_add workgroup scope -> ds_add_f32). Linear table; lane
// sub's 4 dims land at acc offsets {sub, sub+16, sub+32, sub+48} (perm layout).
// Epilogue emits LINEAR y + fused out RMW. ----
__global__ __launch_bounds__(256)
void spmm_sweep_kernel(const unsigned short* __restrict__ rl, const unsigned* __restrict__ cs,
                       const int* __restrict__ bcur, const unsigned* __restrict__ x,
                       unsigned* __restrict__ y, float* __restrict__ out,
                       const float* __restrict__ w, int f) {
    __shared__ float acc[RPB * ASTRIDE];   // 76,180 B
    int b = blockIdx.x, t = threadIdx.x;
    int s = b * CAP, e = min(bcur[b], s + CAP);
    for (int i = t; i < RPB * ASTRIDE; i += 256) acc[i] = 0.f;
    __syncthreads();
    int wid = t >> 6, q = (t >> 4) & 3, sub = t & 15;
    for (int kb = s + wid * 4 + q; kb < e; kb += 16) {
        unsigned ed = cs[kb];
        int r = rl[kb];
        unsigned g = x[((size_t)(ed >> 14) << 4) + sub];
        float vv = __uint_as_float((ed & 0x3FFFu) << 18);
        v2f lo = __builtin_amdgcn_cvt_pk_f32_fp8((int)g, false);
        v2f hi = __builtin_amdgcn_cvt_pk_f32_fp8((int)g, true);
        int a = r * ASTRIDE + sub;
        __hip_atomic_fetch_add(&acc[a],      vv * lo.x, __ATOMIC_RELAXED, __HIP_MEMORY_SCOPE_WORKGROUP);
        __hip_atomic_fetch_add(&acc[a + 16], vv * lo.y, __ATOMIC_RELAXED, __HIP_MEMORY_SCOPE_WORKGROUP);
        __hip_atomic_fetch_add(&acc[a + 32], vv * hi.x, __ATOMIC_RELAXED, __HIP_MEMORY_SCOPE_WORKGROUP);
        __hip_atomic_fetch_add(&acc[a + 48], vv * hi.y, __ATOMIC_RELAXED, __HIP_MEMORY_SCOPE_WORKGROUP);
    }
    __syncthreads();
    float c = w[f] * (0.25f / 64.f);
    int wd = t & 15;
    for (int rr = (t >> 4); rr < RPB; rr += 16) {
        int row = b * RPB + rr;
        if (row >= N_TOTAL) break;
        float a0 = acc[rr * ASTRIDE + wd];          // dim 4wd
        float a1 = acc[rr * ASTRIDE + wd + 16];     // dim 4wd+1
        float a2 = acc[rr * ASTRIDE + wd + 32];     // dim 4wd+2
        float a3 = acc[rr * ASTRIDE + wd + 48];     // dim 4wd+3
        int p = __builtin_amdgcn_cvt_pk_fp8_f32(a0, a1, 0, false);
        p = __builtin_amdgcn_cvt_pk_fp8_f32(a2, a3, p, true);
        y[((size_t)row << 4) + wd] = (unsigned)p;   // linear layout
        float4* o4 = reinterpret_cast<float4*>(out) + (((size_t)row << 4) + wd);
        float4 cv = *o4;
        cv.x += c * a0;
        cv.y += c * a1;
        cv.z += c * a2;
        cv.w += c * a3;
        *o4 = cv;
    }
}

extern "C" void kernel_launch(void* const* d_in, const int* in_sizes, int n_in,
                              void* d_out, int out_size, void* d_ws, size_t ws_size,
                              hipStream_t stream) {
    const float* emb[3]  = {(const float*)d_in[0], (const float*)d_in[1], (const float*)d_in[2]};
    const int*   gidx[3] = {(const int*)d_in[3],   (const int*)d_in[5],   (const int*)d_in[7]};
    const float* gval[3] = {(const float*)d_in[4], (const float*)d_in[6], (const float*)d_in[8]};
    const float* w = (const float*)d_in[9];
    float* out = (float*)d_out;

    const int nnz = in_sizes[4];
    const size_t bufElems = (size_t)N_TOTAL * DIM;       // 9.6M
    const size_t fp8Bytes = bufElems;                    // 9.6 MB per table
    const size_t capElems = (size_t)NBUCK * CAP;         // 5.31M entries

    char* base = (char*)d_ws;
    uint2*          binned = (uint2*)base;                       // 42.47 MB
    unsigned*       emb8   = (unsigned*)base;                    // alias (dead binned)
    unsigned*       bufA8  = (unsigned*)(base + fp8Bytes);
    unsigned*       bufB8  = (unsigned*)(base + 2 * fp8Bytes);
    unsigned*       cs     = (unsigned*)(base + capElems * 8);   // 21.23 MB
    unsigned short* rl     = (unsigned short*)(base + capElems * 8 + capElems * 4);  // 10.62 MB
    int*            rlo12  = (int*)rl;                           // factors 1-2 (+fallback f0)
    int*            rhi12  = rlo12 + N_TOTAL;
    int*            bcur   = (int*)(base + capElems * 14);
    // hybrid-only extension (factor 0 row-grouped CSR):
    unsigned*       csr0   = (unsigned*)((char*)bcur + 4096);
    int*            f0rlo  = (int*)(csr0 + capElems);
    int*            f0rhi  = f0rlo + N_TOTAL;
    const size_t needHybrid = capElems * 14 + 4096 + capElems * 4
                            + (size_t)2 * N_TOTAL * 4;           // ~100.4 MB
    const bool hybrid = ws_size >= needHybrid;

    const int n4 = (int)(bufElems / 4);
    const int n8 = (int)(bufElems / 8);
    dim3 eltGrid((n4 + 255) / 256);
    dim3 cvtGrid((n8 + 255) / 256);
    dim3 chunkGrid((nnz + CHUNK - 1) / CHUNK);            // 586
    dim3 rowGrid((unsigned)(((size_t)N_TOTAL * 64 + 255) / 256));

    init_out_kernel<<<eltGrid, 256, 0, stream>>>(emb[0], emb[1], emb[2], w, out, n4);

    for (int f = 0; f < 3; ++f) {
        fill_bcur_kernel<<<2, 256, 0, stream>>>(bcur);
        bin_kernel<<<chunkGrid, 512, 0, stream>>>(gidx[f], gval[f], bcur, binned, nnz);

        if (f == 0 && hybrid) {
            // A/B probe: layer 0 via sweep (col-sorted), layers 1-2 via reg path.
            scatterc_col_kernel<<<NBUCK, 256, 0, stream>>>(binned, bcur, rl, cs);
            scatterc_row_kernel<<<NBUCK, 256, 0, stream>>>(binned, bcur, f0rlo, f0rhi, csr0);
            conv_fp8_kernel<<<cvtGrid, 256, 0, stream>>>(emb[0], (uint2*)emb8, n8);
            spmm_sweep_kernel<<<NBUCK, 256, 0, stream>>>(rl, cs, bcur, emb8, bufA8, out, w, 0);
            spmm_reg_kernel<false><<<rowGrid, 256, 0, stream>>>(f0rlo, f0rhi, csr0, bufA8, bufB8,
                                                                out, w, 0, N_TOTAL);
            spmm_reg_kernel<true><<<rowGrid, 256, 0, stream>>>(f0rlo, f0rhi, csr0, bufB8, nullptr,
                                                               out, w, 0, N_TOTAL);
        } else {
            scatterc_row_kernel<<<NBUCK, 256, 0, stream>>>(binned, bcur, rlo12, rhi12, cs);
            conv_fp8_kernel<<<cvtGrid, 256, 0, stream>>>(emb[f], (uint2*)emb8, n8);
            spmm_reg_kernel<false><<<rowGrid, 256, 0, stream>>>(rlo12, rhi12, cs, emb8, bufA8,
                                                                out, w, f, N_TOTAL);
            spmm_reg_kernel<false><<<rowGrid, 256, 0, stream>>>(rlo12, rhi12, cs, bufA8, bufB8,
                                                                out, w, f, N_TOTAL);
            spmm_reg_kernel<true><<<rowGrid, 256, 0, stream>>>(rlo12, rhi12, cs, bufB8, nullptr,
                                                               out, w, f, N_TOTAL);
        }
    }
}

// Round 13
// 1093.286 us; speedup vs baseline: 13.2524x; 2.4587x over previous
//
#include <hip/hip_runtime.h>

#define N_TOTAL 150000   // N_USERS + M_ITEMS
#define DIM 64
#define RPB 293          // rows per bucket
#define NBUCK 512        // buckets
#define MAGIC 14658592u  // ceil(2^32/293): __umulhi(r,MAGIC) == r/293 for r<2^24
#define CAP 10368        // bucket capacity (mean 9375 + ~10 sigma)
#define CHUNK 8192       // edges per binning block (512 thr x 16)

typedef float v2f __attribute__((ext_vector_type(2)));

__global__ void fill_bcur_kernel(int* __restrict__ bcur) {
    int t = blockIdx.x * 256 + threadIdx.x;
    if (t < NBUCK) bcur[t] = t * CAP;
}

// Phase B: LDS-sorted multisplit into 512 row-range buckets; coalesced stream-out.
// record: pk.x = rowLocal(9b)<<18 | col(18b) ; pk.y = f32 val bits
__global__ void bin_kernel(const int* __restrict__ idx, const float* __restrict__ val,
                           int* __restrict__ bcur, uint2* __restrict__ binned, int nnz) {
    __shared__ uint2 sedge[CHUNK];        // 64 KB
    __shared__ int lcnt[NBUCK];
    __shared__ int lstart[NBUCK + 1];
    __shared__ int gbase[NBUCK];
    int t = threadIdx.x;
    int base = blockIdx.x * CHUNK;
    int nEdges = min(CHUNK, nnz - base);
    lcnt[t] = 0;
    __syncthreads();
    uint2 myedge[16];
    int myb[16];
    #pragma unroll
    for (int i = 0; i < 16; ++i) {
        int e = base + t + i * 512;
        if (e < nnz) {
            int r = idx[e];
            int b = (int)__umulhi((unsigned)r, MAGIC);
            myb[i] = b;
            unsigned rloc = (unsigned)(r - b * RPB);
            myedge[i].x = (rloc << 18) | (unsigned)idx[nnz + e];
            myedge[i].y = __float_as_uint(val[e]);
            atomicAdd(&lcnt[b], 1);
        } else {
            myb[i] = -1;
        }
    }
    __syncthreads();
    int c = lcnt[t];
    lstart[t] = c;
    __syncthreads();
    for (int off = 1; off < 512; off <<= 1) {
        int x = (t >= off) ? lstart[t - off] : 0;
        __syncthreads();
        lstart[t] += x;
        __syncthreads();
    }
    int incl = lstart[t];
    __syncthreads();
    lstart[t] = incl - c;                  // exclusive
    if (t == 511) lstart[512] = incl;      // total
    gbase[t] = c ? atomicAdd(&bcur[t], c) : 0;
    lcnt[t] = 0;                           // reuse as placement cursor
    __syncthreads();
    #pragma unroll
    for (int i = 0; i < 16; ++i) {
        int b = myb[i];
        if (b >= 0) {
            int o = atomicAdd(&lcnt[b], 1);
            sedge[lstart[b] + o] = myedge[i];
        }
    }
    __syncthreads();
    for (int p = t; p < nEdges; p += 512) {
        int lo = 0, hi = NBUCK;
        while (hi - lo > 1) {
            int mid = (lo + hi) >> 1;
            if (lstart[mid] <= p) lo = mid; else hi = mid;
        }
        int dst = gbase[lo] + (p - lstart[lo]);
        if (dst < (lo + 1) * CAP)          // overflow guard (never hit)
            binned[dst] = sedge[p];
    }
}

// Phase C: per-bucket ROW-grouped CSR -> cs (col<<14|val14) + rlo/rhi (absolute).
__global__ void scatterc_kernel(const uint2* __restrict__ binned,
                                const int* __restrict__ bcur,
                                int* __restrict__ rlo, int* __restrict__ rhi,
                                unsigned* __restrict__ cs) {
    __shared__ int hist[RPB];
    __shared__ int ssc[256];
    int b = blockIdx.x, t = threadIdx.x;
    int s = b * CAP, e = min(bcur[b], s + CAP);
    for (int i = t; i < RPB; i += 256) hist[i] = 0;
    __syncthreads();
    for (int k = s + t; k < e; k += 256)
        atomicAdd(&hist[binned[k].x >> 18], 1);
    __syncthreads();
    int i0 = 2 * t;
    int c0 = (i0 < RPB) ? hist[i0] : 0;
    int c1 = (i0 + 1 < RPB) ? hist[i0 + 1] : 0;
    int s2 = c0 + c1;
    ssc[t] = s2;
    __syncthreads();
    for (int off = 1; off < 256; off <<= 1) {
        int x = (t >= off) ? ssc[t - off] : 0;
        __syncthreads();
        ssc[t] += x;
        __syncthreads();
    }
    int excl = ssc[t] - s2;
    __syncthreads();
    int base0 = s + excl, base1 = s + excl + c0;
    if (i0 < RPB) {
        int row = b * RPB + i0;
        if (row < N_TOTAL) { rlo[row] = base0; rhi[row] = base0 + c0; }
        hist[i0] = base0;
    }
    if (i0 + 1 < RPB) {
        int row = b * RPB + i0 + 1;
        if (row < N_TOTAL) { rlo[row] = base1; rhi[row] = base1 + c1; }
        hist[i0 + 1] = base1;
    }
    __syncthreads();
    for (int k = s + t; k < e; k += 256) {
        uint2 ed = binned[k];
        int rl_ = ed.x >> 18;
        int o = atomicAdd(&hist[rl_], 1);
        unsigned v14 = (ed.y + 0x20000u) >> 18;   // round f32 -> 14-bit float
        cs[o] = ((ed.x & 0x3FFFFu) << 14) | v14;
    }
}

// f32 -> fp8(e4m3, x64 scale) LINEAR table (word w = dims 4w..4w+3).
__global__ void conv_fp8_kernel(const float* __restrict__ x, uint2* __restrict__ y, int n8) {
    int i = blockIdx.x * blockDim.x + threadIdx.x;
    if (i >= n8) return;
    const float4* x4 = reinterpret_cast<const float4*>(x);
    float4 a = x4[2 * i], b = x4[2 * i + 1];
    int p0 = __builtin_amdgcn_cvt_pk_fp8_f32(a.x * 64.f, a.y * 64.f, 0, false);
    p0 = __builtin_amdgcn_cvt_pk_fp8_f32(a.z * 64.f, a.w * 64.f, p0, true);
    int p1 = __builtin_amdgcn_cvt_pk_fp8_f32(b.x * 64.f, b.y * 64.f, 0, false);
    p1 = __builtin_amdgcn_cvt_pk_fp8_f32(b.z * 64.f, b.w * 64.f, p1, true);
    uint2 o;
    o.x = (unsigned)p0;
    o.y = (unsigned)p1;
    y[i] = o;
}

// ---- register-accumulator pull SpMM. One wave per row; quarter-wave (16
// lanes x u32 = 4 fp8 dims) per edge, 4 edges concurrent + 4-deep pipeline.
// Writes ONLY the fp8 y-table (no out RMW -- combine pass handles out). ----
__global__ void spmm_fp8_kernel(const int* __restrict__ rlo, const int* __restrict__ rhi,
                                const unsigned* __restrict__ cs, const unsigned* __restrict__ x,
                                unsigned* __restrict__ y, int nrows) {
    int gid = blockIdx.x * blockDim.x + threadIdx.x;
    int row = gid >> 6;
    int lane = gid & 63;
    if (row >= nrows) return;
    int s = rlo[row], e = rhi[row];
    int q = lane >> 4, sub = lane & 15;
    float ac[4][4];
    #pragma unroll
    for (int j = 0; j < 4; ++j) {
        ac[j][0] = 0.f; ac[j][1] = 0.f; ac[j][2] = 0.f; ac[j][3] = 0.f;
    }
    int k = s + q;
    for (; k + 12 < e; k += 16) {
        unsigned ed[4], g[4];
        #pragma unroll
        for (int j = 0; j < 4; ++j) ed[j] = cs[k + 4 * j];
        #pragma unroll
        for (int j = 0; j < 4; ++j) g[j] = x[((size_t)(ed[j] >> 14) << 4) + sub];
        #pragma unroll
        for (int j = 0; j < 4; ++j) {
            float vv = __uint_as_float((ed[j] & 0x3FFFu) << 18);
            v2f lo = __builtin_amdgcn_cvt_pk_f32_fp8((int)g[j], false);
            v2f hi = __builtin_amdgcn_cvt_pk_f32_fp8((int)g[j], true);
            ac[j][0] += vv * lo.x;
            ac[j][1] += vv * lo.y;
            ac[j][2] += vv * hi.x;
            ac[j][3] += vv * hi.y;
        }
    }
    for (; k < e; k += 4) {
        unsigned ed = cs[k];
        unsigned g = x[((size_t)(ed >> 14) << 4) + sub];
        float vv = __uint_as_float((ed & 0x3FFFu) << 18);
        v2f lo = __builtin_amdgcn_cvt_pk_f32_fp8((int)g, false);
        v2f hi = __builtin_amdgcn_cvt_pk_f32_fp8((int)g, true);
        ac[0][0] += vv * lo.x;
        ac[0][1] += vv * lo.y;
        ac[0][2] += vv * hi.x;
        ac[0][3] += vv * hi.y;
    }
    float a0 = (ac[0][0] + ac[1][0]) + (ac[2][0] + ac[3][0]);
    float a1 = (ac[0][1] + ac[1][1]) + (ac[2][1] + ac[3][1]);
    float a2 = (ac[0][2] + ac[1][2]) + (ac[2][2] + ac[3][2]);
    float a3 = (ac[0][3] + ac[1][3]) + (ac[2][3] + ac[3][3]);
    a0 += __shfl_xor(a0, 16); a0 += __shfl_xor(a0, 32);
    a1 += __shfl_xor(a1, 16); a1 += __shfl_xor(a1, 32);
    a2 += __shfl_xor(a2, 16); a2 += __shfl_xor(a2, 32);
    a3 += __shfl_xor(a3, 16); a3 += __shfl_xor(a3, 32);
    if (q == 0) {
        int p = __builtin_amdgcn_cvt_pk_fp8_f32(a0, a1, 0, false);
        p = __builtin_amdgcn_cvt_pk_fp8_f32(a2, a3, p, true);
        y[((size_t)row << 4) + sub] = (unsigned)p;
    }
}

// ---- per-factor combine: out (+)= (w[f]/4) * (emb + (A+B+C)/64).
// Word i covers dims 4(i&15).. of row i>>4 == float4 index i of emb/out. ----
template <bool FIRST>
__global__ void combine_kernel(const float* __restrict__ emb, const unsigned* __restrict__ A,
                               const unsigned* __restrict__ B, const unsigned* __restrict__ C,
                               const float* __restrict__ w, int f, float* __restrict__ out,
                               int nwords) {
    int i = blockIdx.x * blockDim.x + threadIdx.x;
    if (i >= nwords) return;
    float c = w[f] * 0.25f;
    const float kInv = 1.f / 64.f;
    float4 e = reinterpret_cast<const float4*>(emb)[i];
    unsigned a = A[i], b = B[i], cc = C[i];
    v2f alo = __builtin_amdgcn_cvt_pk_f32_fp8((int)a, false);
    v2f ahi = __builtin_amdgcn_cvt_pk_f32_fp8((int)a, true);
    v2f blo = __builtin_amdgcn_cvt_pk_f32_fp8((int)b, false);
    v2f bhi = __builtin_amdgcn_cvt_pk_f32_fp8((int)b, true);
    v2f clo = __builtin_amdgcn_cvt_pk_f32_fp8((int)cc, false);
    v2f chi = __builtin_amdgcn_cvt_pk_f32_fp8((int)cc, true);
    float4 o;
    o.x = c * (e.x + (alo.x + blo.x + clo.x) * kInv);
    o.y = c * (e.y + (alo.y + blo.y + clo.y) * kInv);
    o.z = c * (e.z + (ahi.x + bhi.x + chi.x) * kInv);
    o.w = c * (e.w + (ahi.y + bhi.y + chi.y) * kInv);
    float4* o4 = reinterpret_cast<float4*>(out) + i;
    if (FIRST) {
        *o4 = o;
    } else {
        float4 cv = *o4;
        cv.x += o.x; cv.y += o.y; cv.z += o.z; cv.w += o.w;
        *o4 = cv;
    }
}

extern "C" void kernel_launch(void* const* d_in, const int* in_sizes, int n_in,
                              void* d_out, int out_size, void* d_ws, size_t ws_size,
                              hipStream_t stream) {
    const float* emb[3]  = {(const float*)d_in[0], (const float*)d_in[1], (const float*)d_in[2]};
    const int*   gidx[3] = {(const int*)d_in[3],   (const int*)d_in[5],   (const int*)d_in[7]};
    const float* gval[3] = {(const float*)d_in[4], (const float*)d_in[6], (const float*)d_in[8]};
    const float* w = (const float*)d_in[9];
    float* out = (float*)d_out;

    const int nnz = in_sizes[4];
    const size_t bufElems = (size_t)N_TOTAL * DIM;       // 9.6M
    const size_t fp8Bytes = bufElems;                    // 9.6 MB per table
    const size_t capElems = (size_t)NBUCK * CAP;         // 5.31M entries

    // ws layout:
    //   [0, 42.5MB)      binned (uint2) -- aliases {emb8, A8, B8, C8} (38.4MB)
    //   [42.5, 63.7MB)   cs (u32, bucket-strided, row-grouped)
    //   then rlo, rhi, bcur   (total < 66 MB)
    char* base = (char*)d_ws;
    uint2*    binned = (uint2*)base;
    unsigned* emb8   = (unsigned*)base;                       // live after scatterc
    unsigned* A8     = (unsigned*)(base + fp8Bytes);
    unsigned* B8     = (unsigned*)(base + 2 * fp8Bytes);
    unsigned* C8     = (unsigned*)(base + 3 * fp8Bytes);
    unsigned* cs     = (unsigned*)(base + capElems * 8);
    int*      rlo    = (int*)(base + capElems * 8 + capElems * 4);
    int*      rhi    = rlo + N_TOTAL;
    int*      bcur   = rhi + N_TOTAL;

    const int n8 = (int)(bufElems / 8);
    const int nwords = (int)(bufElems / 4);               // N_TOTAL*16
    dim3 cvtGrid((n8 + 255) / 256);
    dim3 cmbGrid((nwords + 255) / 256);
    dim3 chunkGrid((nnz + CHUNK - 1) / CHUNK);            // 586
    dim3 rowGrid((unsigned)(((size_t)N_TOTAL * 64 + 255) / 256));

    for (int f = 0; f < 3; ++f) {
        // --- bucket build ---
        fill_bcur_kernel<<<2, 256, 0, stream>>>(bcur);
        bin_kernel<<<chunkGrid, 512, 0, stream>>>(gidx[f], gval[f], bcur, binned, nnz);
        scatterc_kernel<<<NBUCK, 256, 0, stream>>>(binned, bcur, rlo, rhi, cs);

        // --- fp8 table of this factor's embedding (binned is dead now) ---
        conv_fp8_kernel<<<cvtGrid, 256, 0, stream>>>(emb[f], (uint2*)emb8, n8);

        // --- 3 propagation layers (y-table only, no out RMW) ---
        spmm_fp8_kernel<<<rowGrid, 256, 0, stream>>>(rlo, rhi, cs, emb8, A8, N_TOTAL);
        spmm_fp8_kernel<<<rowGrid, 256, 0, stream>>>(rlo, rhi, cs, A8, B8, N_TOTAL);
        spmm_fp8_kernel<<<rowGrid, 256, 0, stream>>>(rlo, rhi, cs, B8, C8, N_TOTAL);

        // --- fold this factor into out ---
        if (f == 0)
            combine_kernel<true><<<cmbGrid, 256, 0, stream>>>(emb[f], A8, B8, C8, w, f,
                                                              out, nwords);
        else
            combine_kernel<false><<<cmbGrid, 256, 0, stream>>>(emb[f], A8, B8, C8, w, f,
                                                               out, nwords);
    }
}

// Round 14
// 986.913 us; speedup vs baseline: 14.6808x; 1.1078x over previous
//
#include <hip/hip_runtime.h>

#define N_TOTAL 150000   // N_USERS + M_ITEMS
#define DIM 64
#define RPB 293          // rows per bucket
#define NBUCK 512        // buckets
#define MAGIC 14658592u  // ceil(2^32/293): __umulhi(r,MAGIC) == r/293 for r<2^24
#define CAP 10368        // bucket capacity (mean 9375 + ~10 sigma)
#define CHUNK 8192       // edges per binning block (512 thr x 16)

typedef float v2f __attribute__((ext_vector_type(2)));

__global__ void fill_bcur_kernel(int* __restrict__ bcur) {
    int t = blockIdx.x * 256 + threadIdx.x;
    if (t < NBUCK) bcur[t] = t * CAP;
}

// Phase B: LDS-sorted multisplit into 512 row-range buckets; coalesced stream-out.
// Global records: bcs[dst] = col(18b)<<14 | val14 ; brl[dst] = rowLocal (u16).
// Bucket is implied by dst/CAP. Stream-out bucket via umulhi on the stored row
// (no binary search).
__global__ void bin_kernel(const int* __restrict__ idx, const float* __restrict__ val,
                           int* __restrict__ bcur, unsigned* __restrict__ bcs,
                           unsigned short* __restrict__ brl, int nnz) {
    __shared__ unsigned scs[CHUNK];       // 32 KB
    __shared__ unsigned srow[CHUNK];      // 32 KB
    __shared__ int lcnt[NBUCK];
    __shared__ int lstart[NBUCK + 1];
    __shared__ int gbase[NBUCK];
    int t = threadIdx.x;
    int base = blockIdx.x * CHUNK;
    int nEdges = min(CHUNK, nnz - base);
    lcnt[t] = 0;
    __syncthreads();
    unsigned mycs[16];
    int myrow[16], myb[16];
    #pragma unroll
    for (int i = 0; i < 16; ++i) {
        int e = base + t + i * 512;
        if (e < nnz) {
            int r = idx[e];
            int b = (int)__umulhi((unsigned)r, MAGIC);
            myb[i] = b;
            myrow[i] = r;
            unsigned v14 = (__float_as_uint(val[e]) + 0x20000u) >> 18;
            mycs[i] = ((unsigned)idx[nnz + e] << 14) | v14;
            atomicAdd(&lcnt[b], 1);
        } else {
            myb[i] = -1;
        }
    }
    __syncthreads();
    int c = lcnt[t];
    lstart[t] = c;
    __syncthreads();
    for (int off = 1; off < 512; off <<= 1) {
        int x = (t >= off) ? lstart[t - off] : 0;
        __syncthreads();
        lstart[t] += x;
        __syncthreads();
    }
    int incl = lstart[t];
    __syncthreads();
    lstart[t] = incl - c;                  // exclusive
    if (t == 511) lstart[512] = incl;      // total
    gbase[t] = c ? atomicAdd(&bcur[t], c) : 0;
    lcnt[t] = 0;                           // reuse as placement cursor
    __syncthreads();
    #pragma unroll
    for (int i = 0; i < 16; ++i) {
        int b = myb[i];
        if (b >= 0) {
            int o = atomicAdd(&lcnt[b], 1);
            int p = lstart[b] + o;
            scs[p] = mycs[i];
            srow[p] = (unsigned)myrow[i];
        }
    }
    __syncthreads();
    for (int p = t; p < nEdges; p += 512) {
        int r = (int)srow[p];
        int b = (int)__umulhi((unsigned)r, MAGIC);
        int dst = gbase[b] + (p - lstart[b]);
        if (dst < (b + 1) * CAP) {         // overflow guard (never hit)
            bcs[dst] = scs[p];
            brl[dst] = (unsigned short)(r - b * RPB);
        }
    }
}

// Phase C: per-bucket ROW-grouped CSR placement -> cs + rlo/rhi (absolute).
__global__ void scatterc_kernel(const unsigned* __restrict__ bcs,
                                const unsigned short* __restrict__ brl,
                                const int* __restrict__ bcur,
                                int* __restrict__ rlo, int* __restrict__ rhi,
                                unsigned* __restrict__ cs) {
    __shared__ int hist[RPB];
    __shared__ int ssc[256];
    int b = blockIdx.x, t = threadIdx.x;
    int s = b * CAP, e = min(bcur[b], s + CAP);
    for (int i = t; i < RPB; i += 256) hist[i] = 0;
    __syncthreads();
    for (int k = s + t; k < e; k += 256)
        atomicAdd(&hist[brl[k]], 1);
    __syncthreads();
    int i0 = 2 * t;
    int c0 = (i0 < RPB) ? hist[i0] : 0;
    int c1 = (i0 + 1 < RPB) ? hist[i0 + 1] : 0;
    int s2 = c0 + c1;
    ssc[t] = s2;
    __syncthreads();
    for (int off = 1; off < 256; off <<= 1) {
        int x = (t >= off) ? ssc[t - off] : 0;
        __syncthreads();
        ssc[t] += x;
        __syncthreads();
    }
    int excl = ssc[t] - s2;
    __syncthreads();
    int base0 = s + excl, base1 = s + excl + c0;
    if (i0 < RPB) {
        int row = b * RPB + i0;
        if (row < N_TOTAL) { rlo[row] = base0; rhi[row] = base0 + c0; }
        hist[i0] = base0;
    }
    if (i0 + 1 < RPB) {
        int row = b * RPB + i0 + 1;
        if (row < N_TOTAL) { rlo[row] = base1; rhi[row] = base1 + c1; }
        hist[i0 + 1] = base1;
    }
    __syncthreads();
    for (int k = s + t; k < e; k += 256) {
        int rl_ = brl[k];
        int o = atomicAdd(&hist[rl_], 1);
        cs[o] = bcs[k];
    }
}

// f32 -> fp8(e4m3, x64 scale) LINEAR table (word w = dims 4w..4w+3).
__global__ void conv_fp8_kernel(const float* __restrict__ x, uint2* __restrict__ y, int n8) {
    int i = blockIdx.x * blockDim.x + threadIdx.x;
    if (i >= n8) return;
    const float4* x4 = reinterpret_cast<const float4*>(x);
    float4 a = x4[2 * i], b = x4[2 * i + 1];
    int p0 = __builtin_amdgcn_cvt_pk_fp8_f32(a.x * 64.f, a.y * 64.f, 0, false);
    p0 = __builtin_amdgcn_cvt_pk_fp8_f32(a.z * 64.f, a.w * 64.f, p0, true);
    int p1 = __builtin_amdgcn_cvt_pk_fp8_f32(b.x * 64.f, b.y * 64.f, 0, false);
    p1 = __builtin_amdgcn_cvt_pk_fp8_f32(b.z * 64.f, b.w * 64.f, p1, true);
    uint2 o;
    o.x = (unsigned)p0;
    o.y = (unsigned)p1;
    y[i] = o;
}

// ---- register-accumulator pull SpMM. One wave per row; EIGHTH-wave (8 lanes
// x uint2 = 8 fp8 dims/lane) per edge; 8 edges concurrent x 2-deep pipeline.
// Writes ONLY the fp8 y-table (combine pass handles out). ----
__global__ void spmm_fp8_kernel(const int* __restrict__ rlo, const int* __restrict__ rhi,
                                const unsigned* __restrict__ cs, const uint2* __restrict__ x2,
                                uint2* __restrict__ y2, int nrows) {
    int gid = blockIdx.x * blockDim.x + threadIdx.x;
    int row = gid >> 6;
    int lane = gid & 63;
    if (row >= nrows) return;
    int s = rlo[row], e = rhi[row];
    int q = lane >> 3, sub = lane & 7;
    float ac[8], bc[8];
    #pragma unroll
    for (int d = 0; d < 8; ++d) { ac[d] = 0.f; bc[d] = 0.f; }
    int k = s + q;
    for (; k + 8 < e; k += 16) {
        unsigned ed0 = cs[k], ed1 = cs[k + 8];
        uint2 g0 = x2[((size_t)(ed0 >> 14) << 3) + sub];
        uint2 g1 = x2[((size_t)(ed1 >> 14) << 3) + sub];
        float v0 = __uint_as_float((ed0 & 0x3FFFu) << 18);
        float v1 = __uint_as_float((ed1 & 0x3FFFu) << 18);
        v2f l0 = __builtin_amdgcn_cvt_pk_f32_fp8((int)g0.x, false);
        v2f h0 = __builtin_amdgcn_cvt_pk_f32_fp8((int)g0.x, true);
        v2f l1 = __builtin_amdgcn_cvt_pk_f32_fp8((int)g0.y, false);
        v2f h1 = __builtin_amdgcn_cvt_pk_f32_fp8((int)g0.y, true);
        ac[0] += v0 * l0.x; ac[1] += v0 * l0.y; ac[2] += v0 * h0.x; ac[3] += v0 * h0.y;
        ac[4] += v0 * l1.x; ac[5] += v0 * l1.y; ac[6] += v0 * h1.x; ac[7] += v0 * h1.y;
        v2f l2 = __builtin_amdgcn_cvt_pk_f32_fp8((int)g1.x, false);
        v2f h2 = __builtin_amdgcn_cvt_pk_f32_fp8((int)g1.x, true);
        v2f l3 = __builtin_amdgcn_cvt_pk_f32_fp8((int)g1.y, false);
        v2f h3 = __builtin_amdgcn_cvt_pk_f32_fp8((int)g1.y, true);
        bc[0] += v1 * l2.x; bc[1] += v1 * l2.y; bc[2] += v1 * h2.x; bc[3] += v1 * h2.y;
        bc[4] += v1 * l3.x; bc[5] += v1 * l3.y; bc[6] += v1 * h3.x; bc[7] += v1 * h3.y;
    }
    for (; k < e; k += 8) {
        unsigned ed = cs[k];
        uint2 g = x2[((size_t)(ed >> 14) << 3) + sub];
        float vv = __uint_as_float((ed & 0x3FFFu) << 18);
        v2f l0 = __builtin_amdgcn_cvt_pk_f32_fp8((int)g.x, false);
        v2f h0 = __builtin_amdgcn_cvt_pk_f32_fp8((int)g.x, true);
        v2f l1 = __builtin_amdgcn_cvt_pk_f32_fp8((int)g.y, false);
        v2f h1 = __builtin_amdgcn_cvt_pk_f32_fp8((int)g.y, true);
        ac[0] += vv * l0.x; ac[1] += vv * l0.y; ac[2] += vv * h0.x; ac[3] += vv * h0.y;
        ac[4] += vv * l1.x; ac[5] += vv * l1.y; ac[6] += vv * h1.x; ac[7] += vv * h1.y;
    }
    #pragma unroll
    for (int d = 0; d < 8; ++d) {
        float a = ac[d] + bc[d];
        a += __shfl_xor(a, 8);
        a += __shfl_xor(a, 16);
        a += __shfl_xor(a, 32);
        ac[d] = a;
    }
    if (q == 0) {
        int p0 = __builtin_amdgcn_cvt_pk_fp8_f32(ac[0], ac[1], 0, false);
        p0 = __builtin_amdgcn_cvt_pk_fp8_f32(ac[2], ac[3], p0, true);
        int p1 = __builtin_amdgcn_cvt_pk_fp8_f32(ac[4], ac[5], 0, false);
        p1 = __builtin_amdgcn_cvt_pk_fp8_f32(ac[6], ac[7], p1, true);
        uint2 o;
        o.x = (unsigned)p0;
        o.y = (unsigned)p1;
        y2[((size_t)row << 3) + sub] = o;
    }
}

__device__ inline float4 dec_sum3(const unsigned* __restrict__ T, int i, int nwords) {
    unsigned a = T[i], b = T[i + nwords], c = T[i + 2 * nwords];
    v2f alo = __builtin_amdgcn_cvt_pk_f32_fp8((int)a, false);
    v2f ahi = __builtin_amdgcn_cvt_pk_f32_fp8((int)a, true);
    v2f blo = __builtin_amdgcn_cvt_pk_f32_fp8((int)b, false);
    v2f bhi = __builtin_amdgcn_cvt_pk_f32_fp8((int)b, true);
    v2f clo = __builtin_amdgcn_cvt_pk_f32_fp8((int)c, false);
    v2f chi = __builtin_amdgcn_cvt_pk_f32_fp8((int)c, true);
    float4 r;
    r.x = alo.x + blo.x + clo.x;
    r.y = alo.y + blo.y + clo.y;
    r.z = ahi.x + bhi.x + chi.x;
    r.w = ahi.y + bhi.y + chi.y;
    return r;
}

// ---- fused combine: out = sum_f (w[f]/4) * (emb_f + (A_f+B_f+C_f)/64) ----
__global__ void combine3_kernel(const float* __restrict__ e0, const float* __restrict__ e1,
                                const float* __restrict__ e2, const unsigned* __restrict__ t0,
                                const unsigned* __restrict__ t1, const unsigned* __restrict__ t2,
                                const float* __restrict__ w, float* __restrict__ out,
                                int nwords) {
    int i = blockIdx.x * blockDim.x + threadIdx.x;
    if (i >= nwords) return;
    const float kInv = 1.f / 64.f;
    float c0 = w[0] * 0.25f, c1 = w[1] * 0.25f, c2 = w[2] * 0.25f;
    float4 ev0 = reinterpret_cast<const float4*>(e0)[i];
    float4 ev1 = reinterpret_cast<const float4*>(e1)[i];
    float4 ev2 = reinterpret_cast<const float4*>(e2)[i];
    float4 s0 = dec_sum3(t0, i, nwords);
    float4 s1 = dec_sum3(t1, i, nwords);
    float4 s2 = dec_sum3(t2, i, nwords);
    float4 o;
    o.x = c0 * (ev0.x + kInv * s0.x) + c1 * (ev1.x + kInv * s1.x) + c2 * (ev2.x + kInv * s2.x);
    o.y = c0 * (ev0.y + kInv * s0.y) + c1 * (ev1.y + kInv * s1.y) + c2 * (ev2.y + kInv * s2.y);
    o.z = c0 * (ev0.z + kInv * s0.z) + c1 * (ev1.z + kInv * s1.z) + c2 * (ev2.z + kInv * s2.z);
    o.w = c0 * (ev0.w + kInv * s0.w) + c1 * (ev1.w + kInv * s1.w) + c2 * (ev2.w + kInv * s2.w);
    reinterpret_cast<float4*>(out)[i] = o;
}

// ---- per-factor combine (fallback when ws too small for 9 live tables) ----
template <bool FIRST>
__global__ void combine_kernel(const float* __restrict__ emb, const unsigned* __restrict__ T,
                               const float* __restrict__ w, int f, float* __restrict__ out,
                               int nwords) {
    int i = blockIdx.x * blockDim.x + threadIdx.x;
    if (i >= nwords) return;
    float c = w[f] * 0.25f;
    const float kInv = 1.f / 64.f;
    float4 e = reinterpret_cast<const float4*>(emb)[i];
    float4 s = dec_sum3(T, i, nwords);
    float4 o;
    o.x = c * (e.x + s.x * kInv);
    o.y = c * (e.y + s.y * kInv);
    o.z = c * (e.z + s.z * kInv);
    o.w = c * (e.w + s.w * kInv);
    float4* o4 = reinterpret_cast<float4*>(out) + i;
    if (FIRST) {
        *o4 = o;
    } else {
        float4 cv = *o4;
        cv.x += o.x; cv.y += o.y; cv.z += o.z; cv.w += o.w;
        *o4 = cv;
    }
}

extern "C" void kernel_launch(void* const* d_in, const int* in_sizes, int n_in,
                              void* d_out, int out_size, void* d_ws, size_t ws_size,
                              hipStream_t stream) {
    const float* emb[3]  = {(const float*)d_in[0], (const float*)d_in[1], (const float*)d_in[2]};
    const int*   gidx[3] = {(const int*)d_in[3],   (const int*)d_in[5],   (const int*)d_in[7]};
    const float* gval[3] = {(const float*)d_in[4], (const float*)d_in[6], (const float*)d_in[8]};
    const float* w = (const float*)d_in[9];
    float* out = (float*)d_out;

    const int nnz = in_sizes[4];
    const size_t bufElems = (size_t)N_TOTAL * DIM;       // 9.6M
    const size_t fp8Bytes = bufElems;                    // 9.6 MB per table
    const size_t capElems = (size_t)NBUCK * CAP;         // 5.31M entries

    // ws layout:
    //   [0, 21.2MB)       bcs  (u32, bucket-strided)  -- emb8 (9.6MB) aliases here
    //   [21.2, 31.9MB)    brl  (u16)
    //   [31.9, 53.1MB)    cs   (u32, row-grouped)
    //   [53.1MB + 4KB]    rlo, rhi, bcur
    //   then              fp8 layer tables (9 if fused combine, else 3)
    char* base = (char*)d_ws;
    unsigned*       bcs  = (unsigned*)base;
    unsigned*       emb8 = (unsigned*)base;                  // alias: live after scatterc
    unsigned short* brl  = (unsigned short*)(base + capElems * 4);
    unsigned*       cs   = (unsigned*)(base + capElems * 6);
    int*            rlo  = (int*)(base + capElems * 10);
    int*            rhi  = rlo + N_TOTAL;
    int*            bcur = rhi + N_TOTAL;
    char*           tab  = base + capElems * 10 + (size_t)2 * N_TOTAL * 4 + 4096;
    const size_t needFused = (tab - base) + (size_t)9 * fp8Bytes;   // ~140.8 MB
    const bool fused = ws_size >= needFused;

    const int n8 = (int)(bufElems / 8);
    const int nwords = (int)(bufElems / 4);               // N_TOTAL*16
    dim3 cvtGrid((n8 + 255) / 256);
    dim3 cmbGrid((nwords + 255) / 256);
    dim3 chunkGrid((nnz + CHUNK - 1) / CHUNK);            // 586
    dim3 rowGrid((unsigned)(((size_t)N_TOTAL * 64 + 255) / 256));

    for (int f = 0; f < 3; ++f) {
        unsigned* A8 = (unsigned*)(tab + (size_t)(fused ? 3 * f + 0 : 0) * fp8Bytes);
        unsigned* B8 = (unsigned*)(tab + (size_t)(fused ? 3 * f + 1 : 1) * fp8Bytes);
        unsigned* C8 = (unsigned*)(tab + (size_t)(fused ? 3 * f + 2 : 2) * fp8Bytes);

        // --- bucket build ---
        fill_bcur_kernel<<<2, 256, 0, stream>>>(bcur);
        bin_kernel<<<chunkGrid, 512, 0, stream>>>(gidx[f], gval[f], bcur, bcs, brl, nnz);
        scatterc_kernel<<<NBUCK, 256, 0, stream>>>(bcs, brl, bcur, rlo, rhi, cs);

        // --- fp8 table of this factor's embedding (bcs region dead now) ---
        conv_fp8_kernel<<<cvtGrid, 256, 0, stream>>>(emb[f], (uint2*)emb8, n8);

        // --- 3 propagation layers (y-table only) ---
        spmm_fp8_kernel<<<rowGrid, 256, 0, stream>>>(rlo, rhi, cs, (const uint2*)emb8,
                                                     (uint2*)A8, N_TOTAL);
        spmm_fp8_kernel<<<rowGrid, 256, 0, stream>>>(rlo, rhi, cs, (const uint2*)A8,
                                                     (uint2*)B8, N_TOTAL);
        spmm_fp8_kernel<<<rowGrid, 256, 0, stream>>>(rlo, rhi, cs, (const uint2*)B8,
                                                     (uint2*)C8, N_TOTAL);

        if (!fused) {
            if (f == 0)
                combine_kernel<true><<<cmbGrid, 256, 0, stream>>>(emb[f], A8, w, f, out, nwords);
            else
                combine_kernel<false><<<cmbGrid, 256, 0, stream>>>(emb[f], A8, w, f, out, nwords);
        }
    }

    if (fused) {
        const unsigned* t0 = (const unsigned*)(tab + (size_t)0 * fp8Bytes);
        const unsigned* t1 = (const unsigned*)(tab + (size_t)3 * fp8Bytes);
        const unsigned* t2 = (const unsigned*)(tab + (size_t)6 * fp8Bytes);
        combine3_kernel<<<cmbGrid, 256, 0, stream>>>(emb[0], emb[1], emb[2], t0, t1, t2,
                                                     w, out, nwords);
    }
}